// Round 9
// baseline (273.675 us; speedup 1.0000x reference)
//
#include <hip/hip_runtime.h>

typedef __attribute__((ext_vector_type(8))) short s16x8;
typedef __attribute__((ext_vector_type(4))) float f32x4;
typedef unsigned int u32;

#define CCH 128

__device__ __forceinline__ ushort f2bf(float f) {
  uint u = __float_as_uint(f);
  u += 0x7fffu + ((u >> 16) & 1u);
  return (ushort)(u >> 16);
}
__device__ __forceinline__ float bf2f(ushort u) {
  return __uint_as_float(((uint)u) << 16);
}

__device__ __forceinline__ void gll16(const void* g, void* l) {
  __builtin_amdgcn_global_load_lds((const __attribute__((address_space(1))) u32*)g,
                                   (__attribute__((address_space(3))) u32*)l, 16, 0, 0);
}

// ---------------- pass1: stats + NCHW fp32 -> pre-swizzled bf16 tile images (r6/r8-proven) ----------------
__global__ __launch_bounds__(256) void pass1(const float* __restrict__ x,
                                             ushort* __restrict__ xb,
                                             float2* __restrict__ partials) {
  __shared__ ushort sT[128 * CCH];  // 32 KiB
  __shared__ float wsa[4][4], wsb[4][4];
  const int t = threadIdx.x;
  const int blk = ((blockIdx.x & 7) << 9) | (blockIdx.x >> 3);  // bijective
  const int b = blk >> 9;
  const int p0 = (blk & 511) << 7;
  const int wv = t >> 6, lane = t & 63;
  const int px4 = (t & 31) * 4;
  const int c8 = t >> 5;  // 0..7

  float sa[4], sq[4];
#pragma unroll
  for (int i = 0; i < 4; ++i) { sa[i] = 0.f; sq[i] = 0.f; }

  const float* xbase = x + (((size_t)b * CCH) << 16) + p0;
#pragma unroll
  for (int i = 0; i < 4; ++i) {
    const int ch = i * 32 + c8 * 4;
    float4 v[4];
#pragma unroll
    for (int j = 0; j < 4; ++j)
      v[j] = *(const float4*)(xbase + (((size_t)(ch + j)) << 16) + px4);
#pragma unroll
    for (int j = 0; j < 4; ++j) {
      sa[i] += v[j].x + v[j].y + v[j].z + v[j].w;
      sq[i] += v[j].x * v[j].x + v[j].y * v[j].y + v[j].z * v[j].z + v[j].w * v[j].w;
    }
    const int c4 = i * 8 + c8;
#pragma unroll
    for (int k = 0; k < 4; ++k) {
      const int row = px4 + k;
      const int gs = c4 ^ (((row >> 3) & 15) << 1);
      ushort4 pk;
      pk.x = f2bf(((const float*)&v[0])[k]);
      pk.y = f2bf(((const float*)&v[1])[k]);
      pk.z = f2bf(((const float*)&v[2])[k]);
      pk.w = f2bf(((const float*)&v[3])[k]);
      *(ushort4*)&sT[row * CCH + gs * 4] = pk;
    }
  }
#pragma unroll
  for (int i = 0; i < 4; ++i) {
    float a = sa[i], q = sq[i];
#pragma unroll
    for (int off = 32; off > 0; off >>= 1) {
      a += __shfl_down(a, off);
      q += __shfl_down(q, off);
    }
    if (lane == 0) { wsa[wv][i] = a; wsb[wv][i] = q; }
  }
  __syncthreads();
  if (t < 8) {
    const int g = t;
    const int w0 = (g & 1) * 2, ii = g >> 1;
    partials[blk * 8 + g] =
        (float2){wsa[w0][ii] + wsa[w0 + 1][ii], wsb[w0][ii] + wsb[w0 + 1][ii]};
  }
  const int g = t & 15, pr = t >> 4;
  ushort* dst = xb + ((size_t)blk << 14);
#pragma unroll
  for (int s = 0; s < 8; ++s) {
    const int row = s * 16 + pr;
    const int sidx = row * CCH + (((2 * g) ^ (((row >> 3) & 15) << 1)) * 4);
    const int didx = row * CCH + ((g ^ (row & 7)) * 8);
    *(s16x8*)&dst[didx] = *(const s16x8*)&sT[sidx];
  }
}

// ---------------- finalize + weight prep (proven) ----------------
__global__ void stats_finalize2(const float2* __restrict__ partials,
                                const float* __restrict__ gn_w,
                                const float* __restrict__ gn_b,
                                float* __restrict__ scale, float* __restrict__ shift) {
  const int t = threadIdx.x;
  const int b = t >> 3, g = t & 7;
  float s1 = 0.f, s2 = 0.f;
  for (int c = 0; c < 512; ++c) {
    float2 p = partials[(b * 512 + c) * 8 + g];
    s1 += p.x;
    s2 += p.y;
  }
  const float invN = 1.0f / 1048576.0f;
  const float mean = s1 * invN;
  const float var = s2 * invN - mean * mean;
  const float rstd = rsqrtf(var + 1e-5f);
  for (int i = 0; i < 16; ++i) {
    const int c = g * 16 + i;
    const float sc = rstd * gn_w[c];
    scale[b * CCH + c] = sc;
    shift[b * CCH + c] = gn_b[c] - mean * sc;
  }
}

__global__ __launch_bounds__(256) void prep_w2(const float* __restrict__ w2,
                                               ushort* __restrict__ w2b) {
  int i = blockIdx.x * 256 + threadIdx.x;
  float4 a = ((const float4*)w2)[i];
  ushort4 o;
  o.x = f2bf(a.x); o.y = f2bf(a.y); o.z = f2bf(a.z); o.w = f2bf(a.w);
  ((ushort4*)w2b)[i] = o;
}

__global__ __launch_bounds__(128) void fold_w1(const float* __restrict__ w1,
                                               const float* __restrict__ b1,
                                               const float* __restrict__ scale,
                                               const float* __restrict__ shift,
                                               ushort* __restrict__ W1b,
                                               float* __restrict__ c1) {
  const int b = blockIdx.x >> 7, o = blockIdx.x & 127, c = threadIdx.x;
  const float wv = w1[o * CCH + c];
  W1b[(b << 14) + o * CCH + c] = f2bf(wv * scale[b * CCH + c]);
  float s = wv * shift[b * CCH + c];
#pragma unroll
  for (int off = 32; off > 0; off >>= 1) s += __shfl_down(s, off);
  __shared__ float tmp[2];
  if ((threadIdx.x & 63) == 0) tmp[threadIdx.x >> 6] = s;
  __syncthreads();
  if (threadIdx.x == 0) c1[(b << 7) + o] = tmp[0] + tmp[1] + b1[o];
}

// ---------------- pass2: 64-px tiles, 2 waves, 8 blocks/CU ----------------
// 8192 blocks (XCD<->batch swizzle). Stage via global_load_lds from pre-swizzled
// image halves; 4 barriers per block; epilogue wave-private (no barriers, no
// store drains); residual re-read from L2/L3-hot xb.
__global__ __launch_bounds__(128, 4) void mlp64(
    const ushort* __restrict__ xb, const ushort* __restrict__ W1b,
    const ushort* __restrict__ w2b, const float* __restrict__ c1,
    const float* __restrict__ b2, float* __restrict__ out) {
  __shared__ float sF[64 * 68];        // 17408 B; first 16 KiB doubles as bf16 tile
  ushort* sB = (ushort*)sF;            // [64 px][128 ch] bf16, granule-XOR swizzled
  const int t = threadIdx.x, lane = t & 63, wv = t >> 6;
  const int fl = lane & 15, fh = lane >> 4;
  const int blk = ((blockIdx.x & 7) << 10) | (blockIdx.x >> 3);  // bijective, XCD<->batch
  const int b = blk >> 10;
  const int p0 = (blk & 1023) << 6;
  const ushort* w1p = W1b + (b << 14);
  const float* c1b = c1 + (b << 7);
  const char* img = (const char*)xb + ((size_t)(blk >> 1) << 15) + ((size_t)(blk & 1) << 14);

  // ---- stage: 16 KiB image half -> LDS, linear (content pre-swizzled by pass1) ----
  {
    const char* src = img + wv * 8192 + lane * 16;
    ushort* dstl = &sB[wv * 4096];
#pragma unroll
    for (int i = 0; i < 8; ++i) gll16(src + i * 1024, dstl + i * 512);
  }
  __builtin_amdgcn_sched_barrier(0);
  asm volatile("s_waitcnt vmcnt(0)" ::: "memory");
  __builtin_amdgcn_sched_barrier(0);
  __builtin_amdgcn_s_barrier();  // B1: xn tile ready
  __builtin_amdgcn_sched_barrier(0);

  // ---- GEMM1: H[hc][px], wave owns hc [wv*64, wv*64+64), all 64 px ----
  f32x4 acc[4][4];
#pragma unroll
  for (int j = 0; j < 4; ++j)
#pragma unroll
    for (int p = 0; p < 4; ++p) acc[j][p] = (f32x4){0.f, 0.f, 0.f, 0.f};

#pragma unroll
  for (int k0 = 0; k0 < 4; ++k0) {
    const int kb = k0 * 32 + fh * 8;
    const int gb = k0 * 4 + fh;
    s16x8 bt[4];
#pragma unroll
    for (int p = 0; p < 4; ++p) {
      const int px = p * 16 + fl;
      bt[p] = *(const s16x8*)&sB[px * CCH + ((gb ^ (px & 7)) << 3)];
    }
#pragma unroll
    for (int j = 0; j < 4; ++j) {
      const s16x8 a = *(const s16x8*)(w1p + (wv * 64 + j * 16 + fl) * CCH + kb);
#pragma unroll
      for (int p = 0; p < 4; ++p)
        acc[j][p] = __builtin_amdgcn_mfma_f32_16x16x32_bf16(a, bt[p], acc[j][p], 0, 0, 0);
    }
  }
  asm volatile("s_waitcnt lgkmcnt(0)" ::: "memory");
  __builtin_amdgcn_sched_barrier(0);
  __builtin_amdgcn_s_barrier();  // B2: xn reads done
  __builtin_amdgcn_sched_barrier(0);

  // ---- H = relu(acc + c1) -> sB (overwrite xn) ----
#pragma unroll
  for (int j = 0; j < 4; ++j) {
    const int hc0 = wv * 64 + j * 16 + fh * 4;
    const float4 cc = *(const float4*)(c1b + hc0);
    const int g = hc0 >> 3, e = hc0 & 7;
#pragma unroll
    for (int p = 0; p < 4; ++p) {
      const int px = p * 16 + fl;
      ushort4 pk;
      pk.x = f2bf(fmaxf(acc[j][p][0] + cc.x, 0.f));
      pk.y = f2bf(fmaxf(acc[j][p][1] + cc.y, 0.f));
      pk.z = f2bf(fmaxf(acc[j][p][2] + cc.z, 0.f));
      pk.w = f2bf(fmaxf(acc[j][p][3] + cc.w, 0.f));
      *(ushort4*)&sB[px * CCH + ((g ^ (px & 7)) << 3) + e] = pk;
    }
  }
  asm volatile("s_waitcnt lgkmcnt(0)" ::: "memory");
  __builtin_amdgcn_sched_barrier(0);
  __builtin_amdgcn_s_barrier();  // B3: H ready
  __builtin_amdgcn_sched_barrier(0);

  // ---- GEMM2: oc striped {f*64 + wv*32 + e*16} ----
  f32x4 acc2[2][2][4];
#pragma unroll
  for (int f = 0; f < 2; ++f)
#pragma unroll
    for (int e = 0; e < 2; ++e)
#pragma unroll
      for (int p = 0; p < 4; ++p) acc2[f][e][p] = (f32x4){0.f, 0.f, 0.f, 0.f};

#pragma unroll
  for (int k0 = 0; k0 < 4; ++k0) {
    const int kb = k0 * 32 + fh * 8;
    const int gb = k0 * 4 + fh;
    s16x8 bt[4];
#pragma unroll
    for (int p = 0; p < 4; ++p) {
      const int px = p * 16 + fl;
      bt[p] = *(const s16x8*)&sB[px * CCH + ((gb ^ (px & 7)) << 3)];
    }
#pragma unroll
    for (int f = 0; f < 2; ++f)
#pragma unroll
      for (int e = 0; e < 2; ++e) {
        const s16x8 a = *(const s16x8*)(w2b + (f * 64 + wv * 32 + e * 16 + fl) * CCH + kb);
#pragma unroll
        for (int p = 0; p < 4; ++p)
          acc2[f][e][p] =
              __builtin_amdgcn_mfma_f32_16x16x32_bf16(a, bt[p], acc2[f][e][p], 0, 0, 0);
      }
  }
  asm volatile("s_waitcnt lgkmcnt(0)" ::: "memory");
  __builtin_amdgcn_sched_barrier(0);
  __builtin_amdgcn_s_barrier();  // B4: H reads done -> sF reusable
  __builtin_amdgcn_sched_barrier(0);

  // ---- epilogue: 2 rounds, wave-private rows [wv*32, wv*32+32), stride 68 ----
#pragma unroll
  for (int f = 0; f < 2; ++f) {
#pragma unroll
    for (int e = 0; e < 2; ++e) {
      const int oc0 = f * 64 + wv * 32 + e * 16 + fh * 4;
      const float4 bbv = *(const float4*)(b2 + oc0);
      const int rloc = wv * 32 + e * 16 + fh * 4;
      const int gr = ((oc0 >> 3) << 4) /*byte*/, er = (oc0 & 7) * 2;
#pragma unroll
      for (int p = 0; p < 4; ++p) {
        const int px = p * 16 + fl;
        const ushort4 rx =
            *(const ushort4*)(img + px * 256 + (((oc0 >> 3) ^ (px & 7)) << 4) + er);
        sF[(rloc + 0) * 68 + px] = acc2[f][e][p][0] + bbv.x + bf2f(rx.x);
        sF[(rloc + 1) * 68 + px] = acc2[f][e][p][1] + bbv.y + bf2f(rx.y);
        sF[(rloc + 2) * 68 + px] = acc2[f][e][p][2] + bbv.z + bf2f(rx.z);
        sF[(rloc + 3) * 68 + px] = acc2[f][e][p][3] + bbv.w + bf2f(rx.w);
      }
    }
    asm volatile("s_waitcnt lgkmcnt(0)" ::: "memory");  // wave-local writes visible
    __builtin_amdgcn_sched_barrier(0);
#pragma unroll
    for (int i = 0; i < 16; ++i) {
      const int rloc = wv * 32 + i * 2 + (lane >> 5);
      const float2 v = *(const float2*)&sF[rloc * 68 + (lane & 31) * 2];
      *(float2*)(out + (((size_t)(b * CCH + f * 64 + rloc)) << 16) + p0 + (lane & 31) * 2) = v;
    }
  }
}

// ---------------- launcher ----------------
extern "C" void kernel_launch(void* const* d_in, const int* in_sizes, int n_in,
                              void* d_out, int out_size, void* d_ws, size_t ws_size,
                              hipStream_t stream) {
  const float* x    = (const float*)d_in[0];
  const float* gn_w = (const float*)d_in[1];
  const float* gn_b = (const float*)d_in[2];
  const float* w1   = (const float*)d_in[3];
  const float* b1   = (const float*)d_in[4];
  const float* w2   = (const float*)d_in[5];
  const float* b2   = (const float*)d_in[6];
  float* out = (float*)d_out;
  char* ws = (char*)d_ws;

  const size_t XB = (size_t)8 * 65536 * CCH * 2;  // 128 MiB pre-swizzled tiles
  ushort* xbuf  = (ushort*)ws;
  float2* parts = (float2*)(ws + XB);             // 256 KiB
  float* scale  = (float*)(ws + XB + 262144);
  float* shift  = (float*)(ws + XB + 266240);
  ushort* w2b   = (ushort*)(ws + XB + 270336);
  ushort* W1b   = (ushort*)(ws + XB + 303104);    // 256 KiB
  float* c1     = (float*)(ws + XB + 565248);

  hipLaunchKernelGGL(pass1, dim3(4096), dim3(256), 0, stream, x, xbuf, parts);
  hipLaunchKernelGGL(stats_finalize2, dim3(1), dim3(64), 0, stream, parts, gn_w, gn_b, scale, shift);
  hipLaunchKernelGGL(fold_w1, dim3(1024), dim3(128), 0, stream, w1, b1, scale, shift, W1b, c1);
  hipLaunchKernelGGL(prep_w2, dim3(16), dim3(256), 0, stream, w2, w2b);
  hipLaunchKernelGGL(mlp64, dim3(8192), dim3(128), 0, stream, xbuf, W1b, w2b, c1, b2, out);
}